// Round 4
// baseline (329.743 us; speedup 1.0000x reference)
//
#include <hip/hip_runtime.h>
#include <math.h>

#define N_BINS_MAX 1024
#define EPS 1e-4f

// Native clang vector types: __builtin_nontemporal_load/store requires these
// (HIP_vector_type int4/float4 pointers are rejected -- R3 compile failure).
typedef int   iv4 __attribute__((ext_vector_type(4)));
typedef float fv4 __attribute__((ext_vector_type(4)));

__global__ __launch_bounds__(256) void pm_kernel(
    const float* __restrict__ bin_centers, int n_bins,
    const int* __restrict__ idx,
    const float* __restrict__ lb,
    const float* __restrict__ ub,
    float* __restrict__ out,
    long long n_rows)
{
    __shared__ float tab0[N_BINS_MAX];
    __shared__ float tab1[N_BINS_MAX];
    __shared__ float tab2[N_BINS_MAX];

    const float lb0 = lb[0], lb1 = lb[1], lb2 = lb[2];
    const float ub0 = ub[0], ub1 = ub[1], ub2 = ub[2];
    const float r0 = 1.0f / (ub0 - lb0 + EPS);
    const float r1 = 1.0f / (ub1 - lb1 + EPS);
    const float r2 = 1.0f / (ub2 - lb2 + EPS);

    // Per-column sigmoid LUTs: 1024 bins x 3 columns = 12 KB LDS.
    for (int i = threadIdx.x; i < n_bins; i += blockDim.x) {
        float c = bin_centers[i];
        float logit = logf(c / (1.0f - c));
        float x0 = (ub0 - logit) * r0;
        float x1 = (ub1 - logit) * r1;
        float x2 = (ub2 - logit) * r2;
        tab0[i] = 1.0f / (1.0f + expf(-x0));
        tab1[i] = 1.0f / (1.0f + expf(-x1));
        tab2[i] = 1.0f / (1.0f + expf(-x2));
    }
    __syncthreads();

    // Hot loop: 2 quads (8 rows) per iteration. All 6 idx int4 loads are
    // issued nontemporally before any use (96 B/lane in flight), both
    // float4 stores are nontemporal: neither stream has any reuse, so
    // skipping L2/L3 allocation removes pure-overhead cache traffic.
    const long long n_quads = n_rows >> 2;
    const long long n_pairs = n_quads >> 1;
    const iv4* __restrict__ idx4 = (const iv4*)idx;
    fv4* __restrict__ out4 = (fv4*)out;
    const long long tid = (long long)blockIdx.x * blockDim.x + threadIdx.x;
    const long long stride = (long long)gridDim.x * blockDim.x;

    for (long long p = tid; p < n_pairs; p += stride) {
        const iv4* base = idx4 + 6 * p;
        iv4 a0 = __builtin_nontemporal_load(base + 0);
        iv4 b0 = __builtin_nontemporal_load(base + 1);
        iv4 c0 = __builtin_nontemporal_load(base + 2);
        iv4 a1 = __builtin_nontemporal_load(base + 3);
        iv4 b1 = __builtin_nontemporal_load(base + 4);
        iv4 c1 = __builtin_nontemporal_load(base + 5);
        fv4 r0v, r1v;
        r0v.x = tab0[a0.x] * tab1[a0.y] * tab2[a0.z];
        r0v.y = tab0[a0.w] * tab1[b0.x] * tab2[b0.y];
        r0v.z = tab0[b0.z] * tab1[b0.w] * tab2[c0.x];
        r0v.w = tab0[c0.y] * tab1[c0.z] * tab2[c0.w];
        r1v.x = tab0[a1.x] * tab1[a1.y] * tab2[a1.z];
        r1v.y = tab0[a1.w] * tab1[b1.x] * tab2[b1.y];
        r1v.z = tab0[b1.z] * tab1[b1.w] * tab2[c1.x];
        r1v.w = tab0[c1.y] * tab1[c1.z] * tab2[c1.w];
        __builtin_nontemporal_store(r0v, out4 + 2 * p + 0);
        __builtin_nontemporal_store(r1v, out4 + 2 * p + 1);
    }

    // Leftover quad (n_quads odd) — none for the bench shape.
    for (long long q = (n_pairs << 1) + tid; q < n_quads; q += stride) {
        iv4 a = idx4[3 * q + 0];
        iv4 b = idx4[3 * q + 1];
        iv4 c = idx4[3 * q + 2];
        fv4 r;
        r.x = tab0[a.x] * tab1[a.y] * tab2[a.z];
        r.y = tab0[a.w] * tab1[b.x] * tab2[b.y];
        r.z = tab0[b.z] * tab1[b.w] * tab2[c.x];
        r.w = tab0[c.y] * tab1[c.z] * tab2[c.w];
        out4[q] = r;
    }

    // Tail rows (n_rows % 4) — none for the bench shape.
    const long long tail_start = n_quads << 2;
    for (long long row = tail_start + tid; row < n_rows; row += stride) {
        int i0 = idx[3 * row + 0];
        int i1 = idx[3 * row + 1];
        int i2 = idx[3 * row + 2];
        out[row] = tab0[i0] * tab1[i1] * tab2[i2];
    }
}

extern "C" void kernel_launch(void* const* d_in, const int* in_sizes, int n_in,
                              void* d_out, int out_size, void* d_ws, size_t ws_size,
                              hipStream_t stream) {
    const float* bin_centers = (const float*)d_in[0];
    const int*   idx         = (const int*)d_in[1];
    const float* lb          = (const float*)d_in[2];
    const float* ub          = (const float*)d_in[3];
    // d_in[4] = operator_number (unused by the math)
    float* out = (float*)d_out;

    int n_bins = in_sizes[0];
    long long n_rows = (long long)in_sizes[1] / 3;

    const int block = 256;
    long long n_pairs = (n_rows >> 2) >> 1;
    long long want = (n_pairs + block - 1) / block;
    if (want < 1) want = 1;
    // 4096 blocks: 16 blocks/CU queued, 8 resident (12 KB LDS, 32 waves/CU).
    // Each thread handles ~2 pairs (4 quads).
    int grid = (int)((want > 4096) ? 4096 : want);

    pm_kernel<<<grid, block, 0, stream>>>(bin_centers, n_bins, idx, lb, ub, out, n_rows);
}

// Round 5
// 299.025 us; speedup vs baseline: 1.1027x; 1.1027x over previous
//
#include <hip/hip_runtime.h>
#include <math.h>

#define N_BINS_MAX 1024
#define EPS 1e-4f

__global__ __launch_bounds__(256) void pm_kernel(
    const float* __restrict__ bin_centers, int n_bins,
    const int* __restrict__ idx,
    const float* __restrict__ lb,
    const float* __restrict__ ub,
    float* __restrict__ out,
    long long n_rows)
{
    __shared__ float tab0[N_BINS_MAX];
    __shared__ float tab1[N_BINS_MAX];
    __shared__ float tab2[N_BINS_MAX];

    const float lb0 = lb[0], lb1 = lb[1], lb2 = lb[2];
    const float ub0 = ub[0], ub1 = ub[1], ub2 = ub[2];
    const float r0 = 1.0f / (ub0 - lb0 + EPS);
    const float r1 = 1.0f / (ub1 - lb1 + EPS);
    const float r2 = 1.0f / (ub2 - lb2 + EPS);

    // Build the per-column sigmoid LUTs: 1024 bins x 3 columns = 12 KB LDS.
    for (int i = threadIdx.x; i < n_bins; i += blockDim.x) {
        float c = bin_centers[i];
        float logit = logf(c / (1.0f - c));
        float x0 = (ub0 - logit) * r0;
        float x1 = (ub1 - logit) * r1;
        float x2 = (ub2 - logit) * r2;
        tab0[i] = 1.0f / (1.0f + expf(-x0));
        tab1[i] = 1.0f / (1.0f + expf(-x1));
        tab2[i] = 1.0f / (1.0f + expf(-x2));
    }
    __syncthreads();

    // Hot loop: 4 rows per thread. Row r uses ints [3r, 3r+2]; a quad of 4
    // rows is 12 consecutive ints = three aligned int4 loads (48 B/lane,
    // fully consumed -> 100% cache-line utilization), one float4 store.
    // NOTE (session ledger): grid-cap=2048 (R1), LDS-coalesced staging (R2),
    // and nontemporal hints (R4, -25us regression: NT defeats the L1/L2 hits
    // that serve the 2nd/3rd touch of each 64B idx line) all tested <= this
    // plain config. Keep cached loads + 1 quad/thread.
    const long long n_quads = n_rows >> 2;
    const int4* __restrict__ idx4 = (const int4*)idx;
    float4* __restrict__ out4 = (float4*)out;
    const long long stride = (long long)gridDim.x * blockDim.x;

    for (long long q = (long long)blockIdx.x * blockDim.x + threadIdx.x;
         q < n_quads; q += stride) {
        int4 a = idx4[3 * q + 0];
        int4 b = idx4[3 * q + 1];
        int4 c = idx4[3 * q + 2];
        float4 r;
        r.x = tab0[a.x] * tab1[a.y] * tab2[a.z];
        r.y = tab0[a.w] * tab1[b.x] * tab2[b.y];
        r.z = tab0[b.z] * tab1[b.w] * tab2[c.x];
        r.w = tab0[c.y] * tab1[c.z] * tab2[c.w];
        out4[q] = r;
    }

    // Tail rows (n_rows % 4) — none for the bench shape, kept for generality.
    const long long tail_start = n_quads << 2;
    for (long long row = tail_start + (long long)blockIdx.x * blockDim.x + threadIdx.x;
         row < n_rows; row += stride) {
        int i0 = idx[3 * row + 0];
        int i1 = idx[3 * row + 1];
        int i2 = idx[3 * row + 2];
        out[row] = tab0[i0] * tab1[i1] * tab2[i2];
    }
}

extern "C" void kernel_launch(void* const* d_in, const int* in_sizes, int n_in,
                              void* d_out, int out_size, void* d_ws, size_t ws_size,
                              hipStream_t stream) {
    const float* bin_centers = (const float*)d_in[0];
    const int*   idx         = (const int*)d_in[1];
    const float* lb          = (const float*)d_in[2];
    const float* ub          = (const float*)d_in[3];
    // d_in[4] = operator_number (unused by the math)
    float* out = (float*)d_out;

    int n_bins = in_sizes[0];
    long long n_rows = (long long)in_sizes[1] / 3;

    const int block = 256;
    long long n_quads = n_rows >> 2;
    long long want = (n_quads + block - 1) / block;
    if (want < 1) want = 1;
    int grid = (int)((want > 16384) ? 16384 : want);

    pm_kernel<<<grid, block, 0, stream>>>(bin_centers, n_bins, idx, lb, ub, out, n_rows);
}